// Round 1
// baseline (664.058 us; speedup 1.0000x reference)
//
#include <hip/hip_runtime.h>

// VEMG2Pose: conv1d -> time-interp -> recurrent MLP rollout -> upsample.
// Key algebraic reductions:
//  - interp(conv(emg)) == conv(interp-window of emg): only 198 time points needed.
//  - conv + first-matmul fold into CW = conv_w_flat @ w1[:512]  (1040x512).
//  - X[t][b][:] = E[t][b][:] @ CW + bX precomputed in parallel; scan only
//    carries the 20-dim prev through small per-batch matvecs.

#define NT   198     // n_time
#define BB   32      // batch
#define CC   16      // emg channels
#define TT   8000    // emg time
#define FF   512     // conv filters
#define KW   65      // conv kernel width
#define HD   512     // hidden
#define OUT  20
#define CJ   (CC*KW) // 1040
#define TOUT 7936    // T - 64
#define NPS  50      // num_pos_steps

// workspace layout (floats)
#define WS_CW 0
#define WS_BX (WS_CW + CJ*HD)          // 532480
#define WS_X  (WS_BX + HD)             // 532992
#define WS_PR (WS_X + NT*BB*HD)        // 532992 + 3244032 = 3777024
// total floats = 3777024 + 32*20*198 = 3903744  (~15.6 MB)

// ---------------- CW = conv_w_flat(F x CJ)^T-contracted with w1x ----------------
// CW[cj][h] = sum_f conv_w[f][cj] * w1[f][h]
__global__ void k_cw(const float* __restrict__ conv_w, const float* __restrict__ w1,
                     float* __restrict__ CW) {
    __shared__ float cw[32][8];
    int cj0 = blockIdx.x * 8;
    int tid = threadIdx.x;
    int hh = tid * 2;
    float acc[8][2] = {};
    for (int f0 = 0; f0 < FF; f0 += 32) {
        __syncthreads();
        int ff = tid >> 3, r = tid & 7;
        cw[ff][r] = conv_w[(f0 + ff) * CJ + cj0 + r];
        __syncthreads();
        #pragma unroll
        for (int f = 0; f < 32; ++f) {
            float wa = w1[(f0 + f) * HD + hh];
            float wb = w1[(f0 + f) * HD + hh + 1];
            #pragma unroll
            for (int r2 = 0; r2 < 8; ++r2) {
                float c = cw[f][r2];
                acc[r2][0] += c * wa;
                acc[r2][1] += c * wb;
            }
        }
    }
    for (int r2 = 0; r2 < 8; ++r2) {
        CW[(cj0 + r2) * HD + hh]     = acc[r2][0];
        CW[(cj0 + r2) * HD + hh + 1] = acc[r2][1];
    }
}

// bX[h] = b1[h] + sum_f conv_b[f] * w1[f][h]
__global__ void k_bx(const float* __restrict__ conv_b, const float* __restrict__ w1,
                     const float* __restrict__ b1, float* __restrict__ bX) {
    int h = threadIdx.x;
    float acc = b1[h];
    for (int f = 0; f < FF; ++f) acc += conv_b[f] * w1[f * HD + h];
    bX[h] = acc;
}

// ---------------- X[t*32+b][h] = E[t][b][:] @ CW + bX ----------------
// E generated on the fly from emg with per-t interp weights (align_corners=True).
__global__ void k_x(const float* __restrict__ emg, const float* __restrict__ CW,
                    const float* __restrict__ bX, float* __restrict__ X) {
    __shared__ float As[32][65];   // [kk][m], +1 pad
    __shared__ float Bs[32][65];   // [kk][n]
    int m0 = blockIdx.x * 64;
    int n0 = blockIdx.y * 64;
    int tid = threadIdx.x;
    int tm = tid & 15, tn = tid >> 4;
    float acc[4][4] = {};
    for (int k0 = 0; k0 < CJ; k0 += 32) {
        __syncthreads();
        int m = tid & 63;
        int kbase = tid >> 6;            // 0..3
        #pragma unroll
        for (int s = 0; s < 8; ++s) {
            int kk = kbase + s * 4;      // 0..31
            int k = k0 + kk;
            float v = 0.f, bv = 0.f;
            if (k < CJ) {
                int row = m0 + m;
                int t = row >> 5, b = row & 31;
                float src = (float)t * (7935.0f / 197.0f);
                float fl = floorf(src);
                int lo = (int)fl;
                float w = src - fl;
                int hi = lo + 1; if (hi > TOUT - 1) hi = TOUT - 1;
                int c = k / KW;
                int j = k - c * KW;
                const float* e = emg + (size_t)(b * CC + c) * TT;
                v = (1.0f - w) * e[lo + j] + w * e[hi + j];
                bv = CW[k * HD + n0 + m];
            }
            As[kk][m] = v;
            Bs[kk][m] = bv;
        }
        __syncthreads();
        #pragma unroll
        for (int kk = 0; kk < 32; ++kk) {
            float a[4], bb[4];
            #pragma unroll
            for (int i = 0; i < 4; ++i) a[i] = As[kk][tm + 16 * i];
            #pragma unroll
            for (int j = 0; j < 4; ++j) bb[j] = Bs[kk][tn + 16 * j];
            #pragma unroll
            for (int i = 0; i < 4; ++i)
                #pragma unroll
                for (int j = 0; j < 4; ++j)
                    acc[i][j] += a[i] * bb[j];
        }
    }
    for (int i = 0; i < 4; ++i) {
        int row = m0 + tm + 16 * i;
        for (int j = 0; j < 4; ++j) {
            int col = n0 + tn + 16 * j;
            X[(size_t)row * HD + col] = acc[i][j] + bX[col];
        }
    }
}

// ---------------- sequential scan: one block per batch element ----------------
__global__ __launch_bounds__(512) void k_scan(
        const float* __restrict__ X, const float* __restrict__ w1,
        const float* __restrict__ w2, const float* __restrict__ b2,
        const float* __restrict__ jang, const int* __restrict__ provide,
        float* __restrict__ preds) {
    __shared__ float h_lds[HD];
    __shared__ float out_lds[2 * OUT];
    __shared__ float prev_lds[OUT];
    int b = blockIdx.x;
    int tid = threadIdx.x;
    int lane = tid & 63, wv = tid >> 6;

    // prev-part weights: w1 rows 512..531, column tid
    float w1p[OUT];
    #pragma unroll
    for (int j = 0; j < OUT; ++j) w1p[j] = w1[(FF + j) * HD + tid];
    // w2 in registers: 5 outputs per wave
    float w2r[5][8];
    #pragma unroll
    for (int q = 0; q < 5; ++q)
        #pragma unroll
        for (int k = 0; k < 8; ++k)
            w2r[q][k] = w2[(lane + 64 * k) * (2 * OUT) + wv * 5 + q];

    if (tid < OUT) {
        int pv = provide[0];
        prev_lds[tid] = pv ? jang[(size_t)(b * OUT + tid) * TT + 32] : 0.0f;
    }
    __syncthreads();

    float xr = X[(size_t)(0 * BB + b) * HD + tid];
    for (int t = 0; t < NT; ++t) {
        float xn = 0.f;
        if (t + 1 < NT) xn = X[(size_t)((t + 1) * BB + b) * HD + tid];
        // phase A: h = relu(X_t + prev @ w1p)
        float hv = xr;
        #pragma unroll
        for (int j = 0; j < OUT; ++j) hv += prev_lds[j] * w1p[j];
        h_lds[tid] = fmaxf(hv, 0.0f);
        __syncthreads();
        // phase B: out = h @ w2 (wave-parallel dot + butterfly reduce)
        #pragma unroll
        for (int q = 0; q < 5; ++q) {
            float s = 0.f;
            #pragma unroll
            for (int k = 0; k < 8; ++k) s += h_lds[lane + 64 * k] * w2r[q][k];
            #pragma unroll
            for (int msk = 32; msk >= 1; msk >>= 1) s += __shfl_xor(s, msk, 64);
            if (lane == 0) out_lds[wv * 5 + q] = s;
        }
        __syncthreads();
        // phase C: pred update
        if (tid < OUT) {
            float pos = out_lds[tid] + b2[tid];
            float vel = out_lds[OUT + tid] + b2[OUT + tid];
            float pr = (t < NPS) ? pos : prev_lds[tid] + vel;
            prev_lds[tid] = pr;
            preds[(size_t)(b * OUT + tid) * NT + t] = pr;
        }
        __syncthreads();
        xr = xn;
    }
}

// ---------------- output kernels ----------------
// pred_up: interp 198 -> 7936, align_corners=False
__global__ void k_up(const float* __restrict__ preds, float* __restrict__ outp) {
    __shared__ float row[NT];
    int rc = blockIdx.x;  // b*20 + ch
    int tid = threadIdx.x;
    if (tid < NT) row[tid] = preds[(size_t)rc * NT + tid];
    __syncthreads();
    const float scale = (float)NT / (float)TOUT;
    for (int i = tid; i < TOUT; i += 256) {
        float src = ((float)i + 0.5f) * scale - 0.5f;
        src = fminf(fmaxf(src, 0.0f), (float)(NT - 1));
        float fl = floorf(src);
        int lo = (int)fl;
        int hi = lo + 1; if (hi > NT - 1) hi = NT - 1;
        float w = src - fl;
        outp[(size_t)rc * TOUT + i] = row[lo] * (1.0f - w) + row[hi] * w;
    }
}

__global__ void k_ja(const float* __restrict__ jang, float* __restrict__ outp) {
    int rc = blockIdx.x;
    int tid = threadIdx.x;
    for (int i = tid; i < TOUT; i += 256)
        outp[(size_t)rc * TOUT + i] = jang[(size_t)rc * TT + 32 + i];
}

__global__ void k_mask(const unsigned char* __restrict__ m, float* __restrict__ outp) {
    int b = blockIdx.x;
    int tid = threadIdx.x;
    for (int i = tid; i < TOUT; i += 256)
        outp[(size_t)b * TOUT + i] = m[(size_t)b * TT + 32 + i] ? 1.0f : 0.0f;
}

extern "C" void kernel_launch(void* const* d_in, const int* in_sizes, int n_in,
                              void* d_out, int out_size, void* d_ws, size_t ws_size,
                              hipStream_t stream) {
    const float* emg     = (const float*)d_in[0];
    const float* jang    = (const float*)d_in[1];
    const unsigned char* msk = (const unsigned char*)d_in[2];
    const int*   provide = (const int*)d_in[3];
    const float* conv_w  = (const float*)d_in[4];
    const float* conv_b  = (const float*)d_in[5];
    const float* w1      = (const float*)d_in[6];
    const float* b1      = (const float*)d_in[7];
    const float* w2      = (const float*)d_in[8];
    const float* b2      = (const float*)d_in[9];
    float* out = (float*)d_out;
    float* ws  = (float*)d_ws;

    float* CW    = ws + WS_CW;
    float* bX    = ws + WS_BX;
    float* X     = ws + WS_X;
    float* preds = ws + WS_PR;

    hipLaunchKernelGGL(k_cw,   dim3(CJ / 8), dim3(256), 0, stream, conv_w, w1, CW);
    hipLaunchKernelGGL(k_bx,   dim3(1),      dim3(HD),  0, stream, conv_b, w1, b1, bX);
    hipLaunchKernelGGL(k_x,    dim3(NT * BB / 64, HD / 64), dim3(256), 0, stream, emg, CW, bX, X);
    hipLaunchKernelGGL(k_scan, dim3(BB),     dim3(512), 0, stream, X, w1, w2, b2, jang, provide, preds);
    hipLaunchKernelGGL(k_up,   dim3(BB * OUT), dim3(256), 0, stream, preds, out);
    hipLaunchKernelGGL(k_ja,   dim3(BB * OUT), dim3(256), 0, stream, jang, out + (size_t)BB * OUT * TOUT);
    hipLaunchKernelGGL(k_mask, dim3(BB),     dim3(256), 0, stream, msk, out + (size_t)2 * BB * OUT * TOUT);
}

// Round 2
// 547.535 us; speedup vs baseline: 1.2128x; 1.2128x over previous
//
#include <hip/hip_runtime.h>

#define NT   198     // n_time
#define BB   32      // batch
#define CC   16      // emg channels
#define TT   8000    // emg time
#define FF   512     // conv filters
#define KW   65      // conv kernel width
#define HD   512     // hidden
#define OUT  20
#define CJ   (CC*KW) // 1040
#define TOUT 7936    // T - 64
#define NPS  50      // num_pos_steps

// workspace layout (floats)
#define WS_CW 0
#define WS_BX (WS_CW + CJ*HD)
#define WS_X  (WS_BX + HD)
#define WS_PR (WS_X + NT*BB*HD)

// ---------------- CW[cj][h] = sum_f conv_w[f][cj] * w1[f][h] ----------------
__global__ void k_cw(const float* __restrict__ conv_w, const float* __restrict__ w1,
                     float* __restrict__ CW) {
    __shared__ float cw[32][8];
    int cj0 = blockIdx.x * 8;
    int tid = threadIdx.x;
    int hh = tid * 2;
    float acc[8][2] = {};
    for (int f0 = 0; f0 < FF; f0 += 32) {
        __syncthreads();
        int ff = tid >> 3, r = tid & 7;
        cw[ff][r] = conv_w[(f0 + ff) * CJ + cj0 + r];
        __syncthreads();
        #pragma unroll
        for (int f = 0; f < 32; ++f) {
            float wa = w1[(f0 + f) * HD + hh];
            float wb = w1[(f0 + f) * HD + hh + 1];
            #pragma unroll
            for (int r2 = 0; r2 < 8; ++r2) {
                float c = cw[f][r2];
                acc[r2][0] += c * wa;
                acc[r2][1] += c * wb;
            }
        }
    }
    for (int r2 = 0; r2 < 8; ++r2) {
        CW[(cj0 + r2) * HD + hh]     = acc[r2][0];
        CW[(cj0 + r2) * HD + hh + 1] = acc[r2][1];
    }
}

// bX[h] = b1[h] + sum_f conv_b[f] * w1[f][h]
__global__ void k_bx(const float* __restrict__ conv_b, const float* __restrict__ w1,
                     const float* __restrict__ b1, float* __restrict__ bX) {
    int h = threadIdx.x;
    float acc = b1[h];
    for (int f = 0; f < FF; ++f) acc += conv_b[f] * w1[f * HD + h];
    bX[h] = acc;
}

// ---------------- X = E @ CW + bX : 128x128x16 tile, 8x8 micro ----------------
__global__ __launch_bounds__(256) void k_x2(const float* __restrict__ emg,
                                            const float* __restrict__ CW,
                                            const float* __restrict__ bX,
                                            float* __restrict__ X) {
    __shared__ float As[16 * 128];
    __shared__ float Bs[16 * 128];
    const int m0 = blockIdx.x * 128;
    const int n0 = blockIdx.y * 128;
    const int tid = threadIdx.x;
    const int tx = tid & 15, ty = tid >> 4;

    // A-load mapping: thread covers row (tid>>1), kk = (tid&1)*8 + s
    const int arow = tid >> 1;
    const int kk0 = (tid & 1) * 8;
    const int grow = m0 + arow;
    const bool rowok = grow < NT * BB;
    const int tt = grow >> 5, bb = grow & 31;
    float src = (float)tt * (7935.0f / 197.0f);
    float fl = floorf(src);
    int lo = (int)fl;
    float w = src - fl;
    int hi = (lo < TOUT - 1) ? lo + 1 : TOUT - 1;

    float acc[8][8] = {};

    for (int k0 = 0; k0 < CJ; k0 += 16) {
        __syncthreads();
        // A: on-the-fly interp of emg
        #pragma unroll
        for (int s = 0; s < 8; ++s) {
            int k = k0 + kk0 + s;
            float v = 0.f;
            if (rowok) {
                int c = k / KW;
                int j = k - c * KW;
                const float* e = emg + (size_t)(bb * CC + c) * TT;
                v = (1.0f - w) * e[lo + j] + w * e[hi + j];
            }
            As[(kk0 + s) * 128 + arow] = v;
        }
        // B: CW tile, float4
        #pragma unroll
        for (int vv = 0; vv < 2; ++vv) {
            int idx = tid * 2 + vv;
            int kb = idx >> 5, n4 = idx & 31;
            *(float4*)&Bs[kb * 128 + n4 * 4] =
                *(const float4*)(CW + (size_t)(k0 + kb) * HD + n0 + n4 * 4);
        }
        __syncthreads();
        #pragma unroll
        for (int kk = 0; kk < 16; ++kk) {
            float4 a0 = *(float4*)&As[kk * 128 + ty * 8];
            float4 a1 = *(float4*)&As[kk * 128 + ty * 8 + 4];
            float4 b0 = *(float4*)&Bs[kk * 128 + tx * 8];
            float4 b1 = *(float4*)&Bs[kk * 128 + tx * 8 + 4];
            float av[8] = {a0.x, a0.y, a0.z, a0.w, a1.x, a1.y, a1.z, a1.w};
            float bv[8] = {b0.x, b0.y, b0.z, b0.w, b1.x, b1.y, b1.z, b1.w};
            #pragma unroll
            for (int i = 0; i < 8; ++i)
                #pragma unroll
                for (int j = 0; j < 8; ++j)
                    acc[i][j] = fmaf(av[i], bv[j], acc[i][j]);
        }
    }

    float bx[8];
    #pragma unroll
    for (int j = 0; j < 8; ++j) bx[j] = bX[n0 + tx * 8 + j];
    #pragma unroll
    for (int i = 0; i < 8; ++i) {
        int r = m0 + ty * 8 + i;
        if (r < NT * BB) {
            float4 o0 = {acc[i][0] + bx[0], acc[i][1] + bx[1], acc[i][2] + bx[2], acc[i][3] + bx[3]};
            float4 o1 = {acc[i][4] + bx[4], acc[i][5] + bx[5], acc[i][6] + bx[6], acc[i][7] + bx[7]};
            *(float4*)(X + (size_t)r * HD + n0 + tx * 8)     = o0;
            *(float4*)(X + (size_t)r * HD + n0 + tx * 8 + 4) = o1;
        }
    }
}

// ---------------- sequential scan: 1 block/batch, 4 waves, reduce-scatter ----
#define RSTAGE(d, n) { \
    const int half = (n) >> 1; \
    const bool up = (lane & (d)) != 0; \
    _Pragma("unroll") \
    for (int i = 0; i < half; ++i) { \
        float send = up ? v[i] : v[i + half]; \
        float keep = up ? v[i + half] : v[i]; \
        float recv = __shfl_xor(send, (d), 64); \
        v[i] = keep + recv; \
    } }

__global__ __launch_bounds__(256) void k_scan(
        const float* __restrict__ X, const float* __restrict__ w1,
        const float* __restrict__ w2, const float* __restrict__ b2,
        const float* __restrict__ jang, const int* __restrict__ provide,
        float* __restrict__ preds) {
    __shared__ float partial[2][8][20];
    const int b = blockIdx.x;
    const int tid = threadIdx.x;
    const int lane = tid & 63, wv = tid >> 6;

    // weights in registers: this thread owns h = 2*tid, 2*tid+1
    float2 w1p[OUT];
    #pragma unroll
    for (int j = 0; j < OUT; ++j)
        w1p[j] = *(const float2*)(w1 + (size_t)(FF + j) * HD + 2 * tid);
    float4 w2p[2][5], w2v[2][5];
    #pragma unroll
    for (int i = 0; i < 2; ++i) {
        const float* wr = w2 + (size_t)(2 * tid + i) * (2 * OUT);
        #pragma unroll
        for (int q = 0; q < 5; ++q) {
            w2p[i][q] = *(const float4*)(wr + 4 * q);
            w2v[i][q] = *(const float4*)(wr + OUT + 4 * q);
        }
    }
    float b2p = 0.f, b2vv = 0.f;
    if (lane < OUT) { b2p = b2[lane]; b2vv = b2[OUT + lane]; }

    // initial prev (broadcast via shuffles), lane-own scalar for vel path
    float ip = 0.f;
    if (lane < OUT && provide[0])
        ip = jang[((size_t)(b * OUT + lane)) * TT + 32];
    float myprev = ip;
    float prev[OUT];
    #pragma unroll
    for (int j = 0; j < OUT; ++j) prev[j] = __shfl(ip, j, 64);

    const float* Xb = X + (size_t)b * HD;
    float2 xc = *(const float2*)(Xb + (size_t)0 * BB * HD + 2 * tid);
    float2 xn = *(const float2*)(Xb + (size_t)1 * BB * HD + 2 * tid);

    for (int t = 0; t < NT; ++t) {
        int tp = (t + 2 < NT) ? t + 2 : NT - 1;
        float2 xf = *(const float2*)(Xb + (size_t)tp * BB * HD + 2 * tid);

        // phase A: h = relu(x + prev @ w1p)
        float h0 = xc.x, h1 = xc.y;
        #pragma unroll
        for (int j = 0; j < OUT; ++j) {
            h0 = fmaf(prev[j], w1p[j].x, h0);
            h1 = fmaf(prev[j], w1p[j].y, h1);
        }
        h0 = fmaxf(h0, 0.f); h1 = fmaxf(h1, 0.f);

        // phase B: only the needed 20 outputs
        float v[32];
        #pragma unroll
        for (int i = OUT; i < 32; ++i) v[i] = 0.f;
        if (t < NPS) {
            #pragma unroll
            for (int q = 0; q < 5; ++q) {
                v[4*q+0] = h0 * w2p[0][q].x + h1 * w2p[1][q].x;
                v[4*q+1] = h0 * w2p[0][q].y + h1 * w2p[1][q].y;
                v[4*q+2] = h0 * w2p[0][q].z + h1 * w2p[1][q].z;
                v[4*q+3] = h0 * w2p[0][q].w + h1 * w2p[1][q].w;
            }
        } else {
            #pragma unroll
            for (int q = 0; q < 5; ++q) {
                v[4*q+0] = h0 * w2v[0][q].x + h1 * w2v[1][q].x;
                v[4*q+1] = h0 * w2v[0][q].y + h1 * w2v[1][q].y;
                v[4*q+2] = h0 * w2v[0][q].z + h1 * w2v[1][q].z;
                v[4*q+3] = h0 * w2v[0][q].w + h1 * w2v[1][q].w;
            }
        }

        // in-wave multi-value reduce: 31 shuffles for all 20 (padded 32) sums.
        // after 5 stages lane holds q=(lane>>1)&31, parity=lane&1 half-sum.
        RSTAGE(32, 32) RSTAGE(16, 16) RSTAGE(8, 8) RSTAGE(4, 4) RSTAGE(2, 2)

        int q = (lane >> 1) & 31, par = lane & 1;
        if (q < OUT) partial[t & 1][wv * 2 + par][q] = v[0];
        __syncthreads();

        float pr = 0.f;
        if (lane < OUT) {
            float s = 0.f;
            #pragma unroll
            for (int p = 0; p < 8; ++p) s += partial[t & 1][p][lane];
            pr = (t < NPS) ? (s + b2p) : (myprev + s + b2vv);
            myprev = pr;
            if (wv == 0) preds[((size_t)(b * OUT + lane)) * NT + t] = pr;
        }
        #pragma unroll
        for (int j = 0; j < OUT; ++j) prev[j] = __shfl(pr, j, 64);
        xc = xn; xn = xf;
    }
}

// ---------------- output kernels ----------------
__global__ void k_up(const float* __restrict__ preds, float* __restrict__ outp) {
    __shared__ float row[NT];
    int rc = blockIdx.x;  // b*20 + ch
    int tid = threadIdx.x;
    if (tid < NT) row[tid] = preds[(size_t)rc * NT + tid];
    __syncthreads();
    const float scale = (float)NT / (float)TOUT;
    for (int i = tid; i < TOUT; i += 256) {
        float src = ((float)i + 0.5f) * scale - 0.5f;
        src = fminf(fmaxf(src, 0.0f), (float)(NT - 1));
        float fl = floorf(src);
        int lo = (int)fl;
        int hi = lo + 1; if (hi > NT - 1) hi = NT - 1;
        float w = src - fl;
        outp[(size_t)rc * TOUT + i] = row[lo] * (1.0f - w) + row[hi] * w;
    }
}

__global__ void k_ja(const float* __restrict__ jang, float* __restrict__ outp) {
    int rc = blockIdx.x;
    int tid = threadIdx.x;
    for (int i = tid; i < TOUT; i += 256)
        outp[(size_t)rc * TOUT + i] = jang[(size_t)rc * TT + 32 + i];
}

__global__ void k_mask(const unsigned char* __restrict__ m, float* __restrict__ outp) {
    int b = blockIdx.x;
    int tid = threadIdx.x;
    for (int i = tid; i < TOUT; i += 256)
        outp[(size_t)b * TOUT + i] = m[(size_t)b * TT + 32 + i] ? 1.0f : 0.0f;
}

extern "C" void kernel_launch(void* const* d_in, const int* in_sizes, int n_in,
                              void* d_out, int out_size, void* d_ws, size_t ws_size,
                              hipStream_t stream) {
    const float* emg     = (const float*)d_in[0];
    const float* jang    = (const float*)d_in[1];
    const unsigned char* msk = (const unsigned char*)d_in[2];
    const int*   provide = (const int*)d_in[3];
    const float* conv_w  = (const float*)d_in[4];
    const float* conv_b  = (const float*)d_in[5];
    const float* w1      = (const float*)d_in[6];
    const float* b1      = (const float*)d_in[7];
    const float* w2      = (const float*)d_in[8];
    const float* b2      = (const float*)d_in[9];
    float* out = (float*)d_out;
    float* ws  = (float*)d_ws;

    float* CW    = ws + WS_CW;
    float* bX    = ws + WS_BX;
    float* X     = ws + WS_X;
    float* preds = ws + WS_PR;

    hipLaunchKernelGGL(k_cw,   dim3(CJ / 8), dim3(256), 0, stream, conv_w, w1, CW);
    hipLaunchKernelGGL(k_bx,   dim3(1),      dim3(HD),  0, stream, conv_b, w1, b1, bX);
    hipLaunchKernelGGL(k_x2,   dim3((NT * BB + 127) / 128, HD / 128), dim3(256), 0, stream,
                       emg, CW, bX, X);
    hipLaunchKernelGGL(k_scan, dim3(BB),     dim3(256), 0, stream, X, w1, w2, b2, jang, provide, preds);
    hipLaunchKernelGGL(k_up,   dim3(BB * OUT), dim3(256), 0, stream, preds, out);
    hipLaunchKernelGGL(k_ja,   dim3(BB * OUT), dim3(256), 0, stream, jang, out + (size_t)BB * OUT * TOUT);
    hipLaunchKernelGGL(k_mask, dim3(BB),     dim3(256), 0, stream, msk, out + (size_t)2 * BB * OUT * TOUT);
}

// Round 4
// 470.935 us; speedup vs baseline: 1.4101x; 1.1627x over previous
//
#include <hip/hip_runtime.h>

#define NT   198     // n_time
#define BB   32      // batch
#define CC   16      // emg channels
#define TT   8000    // emg time
#define FF   512     // conv filters
#define KW   65      // conv kernel width
#define HD   512     // hidden
#define OUT  20
#define CJ   (CC*KW) // 1040
#define TOUT 7936    // T - 64
#define NPS  50      // num_pos_steps

typedef float f4 __attribute__((ext_vector_type(4)));
typedef unsigned u2 __attribute__((ext_vector_type(2)));

// workspace layout (floats)
#define WS_CW 0
#define WS_BX (WS_CW + CJ*HD)
#define WS_X  (WS_BX + HD)
#define WS_PR (WS_X + NT*BB*HD)

// ---------------- CW[cj][h] = sum_f conv_w[f][cj] * w1[f][h] ----------------
__global__ void k_cw(const float* __restrict__ conv_w, const float* __restrict__ w1,
                     float* __restrict__ CW) {
    __shared__ float cw[32][8];
    int cj0 = blockIdx.x * 8;
    int tid = threadIdx.x;
    int hh = tid * 2;
    float acc[8][2] = {};
    for (int f0 = 0; f0 < FF; f0 += 32) {
        __syncthreads();
        int ff = tid >> 3, r = tid & 7;
        cw[ff][r] = conv_w[(f0 + ff) * CJ + cj0 + r];
        __syncthreads();
        #pragma unroll
        for (int f = 0; f < 32; ++f) {
            float wa = w1[(f0 + f) * HD + hh];
            float wb = w1[(f0 + f) * HD + hh + 1];
            #pragma unroll
            for (int r2 = 0; r2 < 8; ++r2) {
                float c = cw[f][r2];
                acc[r2][0] += c * wa;
                acc[r2][1] += c * wb;
            }
        }
    }
    for (int r2 = 0; r2 < 8; ++r2) {
        CW[(cj0 + r2) * HD + hh]     = acc[r2][0];
        CW[(cj0 + r2) * HD + hh + 1] = acc[r2][1];
    }
}

// bX[h] = b1[h] + sum_f conv_b[f] * w1[f][h]
__global__ void k_bx(const float* __restrict__ conv_b, const float* __restrict__ w1,
                     const float* __restrict__ b1, float* __restrict__ bX) {
    int h = threadIdx.x;
    float acc = b1[h];
    for (int f = 0; f < FF; ++f) acc += conv_b[f] * w1[f * HD + h];
    bX[h] = acc;
}

// ------- X[b*198+t][h] = E[t][b][:] @ CW + bX : 64x64x32 tile, 4x4 micro ----
__global__ __launch_bounds__(256) void k_x3(const float* __restrict__ emg,
                                            const float* __restrict__ CW,
                                            const float* __restrict__ bX,
                                            float* __restrict__ X) {
    __shared__ float As[32][68];
    __shared__ float Bs[32][68];
    const int m0 = blockIdx.x * 64;
    const int n0 = blockIdx.y * 64;
    const int tid = threadIdx.x;
    const int tx = tid & 15, ty = tid >> 4;

    // A-staging: fixed row per thread, 8 consecutive kk
    const int am = tid & 63;
    const int kbase = (tid >> 6) * 8;     // 0,8,16,24 (wave-uniform)
    const int grow = m0 + am;             // = b*198 + t
    const int bb = grow / NT;
    const int tt = grow - bb * NT;
    const float src = (float)tt * (7935.0f / 197.0f);
    const float fl = floorf(src);
    const int lo = (int)fl;
    const float w = src - fl;
    const int dhi = (w > 0.0f) ? 1 : 0;   // hi==lo when w==0 (keeps loads in-bounds)
    const float* ebase = emg + (size_t)bb * CC * TT + lo;
    int c = 0, j = kbase;                 // k = c*65 + j, tracked incrementally

    f4 acc[4] = {};   // acc[i] = 4 output cols for row i

    for (int kt = 0; kt < 33; ++kt) {
        const int k0 = kt * 32;
        __syncthreads();
        // A: on-the-fly interp (no division in the loop)
        #pragma unroll
        for (int s = 0; s < 8; ++s) {
            int js = j + s, cs = c;
            if (js >= KW) { js -= KW; cs += 1; }
            float v = 0.f;
            if (k0 + kbase + s < CJ) {
                const float* p = ebase + cs * TT + js;
                v = (1.0f - w) * p[0] + w * p[dhi];
            }
            As[kbase + s][am] = v;
        }
        // B: CW tile, two float4 rows per thread
        {
            int kb = tid >> 4, c4 = tid & 15;
            int k = k0 + kb;
            f4 bv = {0.f, 0.f, 0.f, 0.f};
            if (k < CJ) bv = *(const f4*)(CW + (size_t)k * HD + n0 + c4 * 4);
            *(f4*)&Bs[kb][c4 * 4] = bv;
            int k2 = k0 + kb + 16;
            f4 bv2 = {0.f, 0.f, 0.f, 0.f};
            if (k2 < CJ) bv2 = *(const f4*)(CW + (size_t)k2 * HD + n0 + c4 * 4);
            *(f4*)&Bs[kb + 16][c4 * 4] = bv2;
        }
        __syncthreads();
        #pragma unroll
        for (int kk = 0; kk < 32; ++kk) {
            f4 a = *(f4*)&As[kk][ty * 4];
            f4 bq = *(f4*)&Bs[kk][tx * 4];
            acc[0] += a[0] * bq;
            acc[1] += a[1] * bq;
            acc[2] += a[2] * bq;
            acc[3] += a[3] * bq;
        }
        j += 32;
        if (j >= KW) { j -= KW; c += 1; }
    }

    f4 bx = *(const f4*)(bX + n0 + tx * 4);
    #pragma unroll
    for (int i = 0; i < 4; ++i) {
        int r = m0 + ty * 4 + i;     // M = 6336 = 99*64 exactly, no guard
        *(f4*)(X + (size_t)r * HD + n0 + tx * 4) = acc[i] + bx;
    }
}

// ---------------- VALU-pipe 64-lane sum (no ds_bpermute) ----------------
template <int CTRL>
__device__ __forceinline__ float dpp_add(float x) {
    int y = __builtin_amdgcn_mov_dpp(__float_as_int(x), CTRL, 0xf, 0xf, true);
    return x + __int_as_float(y);
}
__device__ __forceinline__ float wave_sum64(float x) {
    x = dpp_add<0xB1>(x);    // quad_perm [1,0,3,2]  : + x[l^1]
    x = dpp_add<0x4E>(x);    // quad_perm [2,3,0,1]  : + x[l^2]
    x = dpp_add<0x140>(x);   // row_mirror           : + opposite quad
    x = dpp_add<0x141>(x);   // row_half_mirror      : row-16 sum, all lanes
    { int y = __builtin_amdgcn_ds_swizzle(__float_as_int(x), 0x401f);  // xor16
      x = x + __int_as_float(y); }
    { u2 r = __builtin_amdgcn_permlane32_swap(__float_as_uint(x),
                                              __float_as_uint(x), false, false);
      x = __uint_as_float(r[0]) + __uint_as_float(r[1]); }  // + x[l^32]
    return x;
}

// ------------- sequential scan: 1 block/batch, 2 waves, DPP reduce ----------
#define SCAN_STEP(T, ISPOS) {                                                  \
    int tp = (T) + 2; if (tp > NT - 1) tp = NT - 1;                            \
    f4 xf = *(const f4*)(Xb + (size_t)tp * HD);                                \
    f4 h = xc;                                                                 \
    _Pragma("unroll")                                                          \
    for (int jj = 0; jj < OUT; ++jj) h += prev[jj] * w1p[jj];                  \
    h[0] = fmaxf(h[0], 0.f); h[1] = fmaxf(h[1], 0.f);                          \
    h[2] = fmaxf(h[2], 0.f); h[3] = fmaxf(h[3], 0.f);                          \
    f4 v[5];                                                                   \
    _Pragma("unroll")                                                          \
    for (int g = 0; g < 5; ++g)                                                \
        v[g] = h[0]*w2r[0][g] + h[1]*w2r[1][g] + h[2]*w2r[2][g] + h[3]*w2r[3][g]; \
    float s[OUT];                                                              \
    _Pragma("unroll")                                                          \
    for (int g = 0; g < 5; ++g) {                                              \
        s[g*4+0] = wave_sum64(v[g][0]); s[g*4+1] = wave_sum64(v[g][1]);        \
        s[g*4+2] = wave_sum64(v[g][2]); s[g*4+3] = wave_sum64(v[g][3]); }      \
    if (wv == 1) {                                                             \
        _Pragma("unroll")                                                      \
        for (int g = 0; g < 5; ++g) {                                          \
            s[g*4+0] += b2r[g][0]; s[g*4+1] += b2r[g][1];                      \
            s[g*4+2] += b2r[g][2]; s[g*4+3] += b2r[g][3]; } }                  \
    if (lane == 0) {                                                           \
        _Pragma("unroll")                                                      \
        for (int g = 0; g < 5; ++g) {                                          \
            f4 o; o[0]=s[g*4]; o[1]=s[g*4+1]; o[2]=s[g*4+2]; o[3]=s[g*4+3];    \
            *(f4*)&part[(T)&1][wv][g*4] = o; } }                               \
    __syncthreads();                                                           \
    _Pragma("unroll")                                                          \
    for (int g = 0; g < 5; ++g) {                                              \
        f4 pa = *(f4*)&part[(T)&1][0][g*4];                                    \
        f4 pb = *(f4*)&part[(T)&1][1][g*4];                                    \
        f4 sm = pa + pb;                                                       \
        if (ISPOS) { prev[g*4+0]=sm[0]; prev[g*4+1]=sm[1];                     \
                     prev[g*4+2]=sm[2]; prev[g*4+3]=sm[3]; }                   \
        else       { prev[g*4+0]+=sm[0]; prev[g*4+1]+=sm[1];                   \
                     prev[g*4+2]+=sm[2]; prev[g*4+3]+=sm[3]; } }               \
    if (tid == 0) {                                                            \
        _Pragma("unroll")                                                      \
        for (int g = 0; g < 5; ++g) {                                          \
            f4 o; o[0]=prev[g*4]; o[1]=prev[g*4+1];                            \
            o[2]=prev[g*4+2]; o[3]=prev[g*4+3];                                \
            *(f4*)(predp + (size_t)(T) * OUT + g*4) = o; } }                   \
    xc = xn; xn = xf; }

__global__ __launch_bounds__(128) void k_scan(
        const float* __restrict__ X, const float* __restrict__ w1,
        const float* __restrict__ w2, const float* __restrict__ b2,
        const float* __restrict__ jang, const int* __restrict__ provide,
        float* __restrict__ preds) {
    __shared__ __align__(16) float part[2][2][24];
    const int b = blockIdx.x;
    const int tid = threadIdx.x;
    const int lane = tid & 63, wv = tid >> 6;
    const int h0 = wv * 256 + lane * 4;   // 4 contiguous h per lane

    f4 w1p[OUT];
    #pragma unroll
    for (int jj = 0; jj < OUT; ++jj)
        w1p[jj] = *(const f4*)(w1 + (size_t)(FF + jj) * HD + h0);

    f4 w2r[4][5];     // pos half first
    #pragma unroll
    for (int i = 0; i < 4; ++i)
        #pragma unroll
        for (int g = 0; g < 5; ++g)
            w2r[i][g] = *(const f4*)(w2 + (size_t)(h0 + i) * (2*OUT) + g*4);
    f4 b2r[5];
    #pragma unroll
    for (int g = 0; g < 5; ++g) b2r[g] = *(const f4*)(b2 + g*4);

    float prev[OUT];
    float pvf = provide[0] ? 1.0f : 0.0f;
    #pragma unroll
    for (int jj = 0; jj < OUT; ++jj)
        prev[jj] = pvf * jang[(size_t)(b * OUT + jj) * TT + 32];

    const float* Xb = X + (size_t)b * NT * HD + h0;
    float* predp = preds + (size_t)b * NT * OUT;
    f4 xc = *(const f4*)(Xb + 0 * HD);
    f4 xn = *(const f4*)(Xb + 1 * HD);

    for (int t = 0; t < NPS; ++t) { SCAN_STEP(t, 1) }

    // switch to velocity half of w2/b2
    #pragma unroll
    for (int i = 0; i < 4; ++i)
        #pragma unroll
        for (int g = 0; g < 5; ++g)
            w2r[i][g] = *(const f4*)(w2 + (size_t)(h0 + i) * (2*OUT) + OUT + g*4);
    #pragma unroll
    for (int g = 0; g < 5; ++g) b2r[g] = *(const f4*)(b2 + OUT + g*4);

    for (int t = NPS; t < NT; ++t) { SCAN_STEP(t, 0) }
}

// ---------------- output kernels ----------------
__global__ void k_up(const float* __restrict__ preds, float* __restrict__ outp) {
    __shared__ float row[NT];
    int rc = blockIdx.x;  // b*20 + ch
    int bq = rc / OUT, ch = rc - bq * OUT;
    int tid = threadIdx.x;
    if (tid < NT) row[tid] = preds[(size_t)(bq * NT + tid) * OUT + ch];
    __syncthreads();
    const float scale = (float)NT / (float)TOUT;
    for (int i = tid; i < TOUT; i += 256) {
        float src = ((float)i + 0.5f) * scale - 0.5f;
        src = fminf(fmaxf(src, 0.0f), (float)(NT - 1));
        float fl = floorf(src);
        int lo = (int)fl;
        int hi = lo + 1; if (hi > NT - 1) hi = NT - 1;
        float w = src - fl;
        outp[(size_t)rc * TOUT + i] = row[lo] * (1.0f - w) + row[hi] * w;
    }
}

__global__ void k_ja(const float* __restrict__ jang, float* __restrict__ outp) {
    int rc = blockIdx.x;
    int tid = threadIdx.x;
    for (int i = tid; i < TOUT; i += 256)
        outp[(size_t)rc * TOUT + i] = jang[(size_t)rc * TT + 32 + i];
}

__global__ void k_mask(const unsigned char* __restrict__ m, float* __restrict__ outp) {
    int b = blockIdx.x;
    int tid = threadIdx.x;
    for (int i = tid; i < TOUT; i += 256)
        outp[(size_t)b * TOUT + i] = m[(size_t)b * TT + 32 + i] ? 1.0f : 0.0f;
}

extern "C" void kernel_launch(void* const* d_in, const int* in_sizes, int n_in,
                              void* d_out, int out_size, void* d_ws, size_t ws_size,
                              hipStream_t stream) {
    const float* emg     = (const float*)d_in[0];
    const float* jang    = (const float*)d_in[1];
    const unsigned char* msk = (const unsigned char*)d_in[2];
    const int*   provide = (const int*)d_in[3];
    const float* conv_w  = (const float*)d_in[4];
    const float* conv_b  = (const float*)d_in[5];
    const float* w1      = (const float*)d_in[6];
    const float* b1      = (const float*)d_in[7];
    const float* w2      = (const float*)d_in[8];
    const float* b2      = (const float*)d_in[9];
    float* out = (float*)d_out;
    float* ws  = (float*)d_ws;

    float* CW    = ws + WS_CW;
    float* bX    = ws + WS_BX;
    float* X     = ws + WS_X;
    float* preds = ws + WS_PR;

    hipLaunchKernelGGL(k_cw,   dim3(CJ / 8), dim3(256), 0, stream, conv_w, w1, CW);
    hipLaunchKernelGGL(k_bx,   dim3(1),      dim3(HD),  0, stream, conv_b, w1, b1, bX);
    hipLaunchKernelGGL(k_x3,   dim3(99, 8),  dim3(256), 0, stream, emg, CW, bX, X);
    hipLaunchKernelGGL(k_scan, dim3(BB),     dim3(128), 0, stream, X, w1, w2, b2, jang, provide, preds);
    hipLaunchKernelGGL(k_up,   dim3(BB * OUT), dim3(256), 0, stream, preds, out);
    hipLaunchKernelGGL(k_ja,   dim3(BB * OUT), dim3(256), 0, stream, jang, out + (size_t)BB * OUT * TOUT);
    hipLaunchKernelGGL(k_mask, dim3(BB),     dim3(256), 0, stream, msk, out + (size_t)2 * BB * OUT * TOUT);
}